// Round 6
// baseline (250.363 us; speedup 1.0000x reference)
//
#include <hip/hip_runtime.h>

typedef unsigned short ushort_t;
typedef unsigned int u32;
typedef __attribute__((ext_vector_type(8))) short short8;
typedef __attribute__((ext_vector_type(4))) float floatx4;

typedef const __attribute__((address_space(1))) u32* gptr_t;
typedef __attribute__((address_space(3))) u32* lptr_t;

__device__ __forceinline__ void async_copy16(void* lds, const void* g) {
  __builtin_amdgcn_global_load_lds((gptr_t)g, (lptr_t)lds, 16, 0, 0);
}

__device__ __forceinline__ ushort_t f2bf(float f) {  // RNE
  u32 u = __float_as_uint(f);
  u += 0x7fffu + ((u >> 16) & 1u);
  return (ushort_t)(u >> 16);
}

__device__ __forceinline__ floatx4 mfma16(short8 a, short8 b, floatx4 c) {
  return __builtin_amdgcn_mfma_f32_16x16x32_bf16(a, b, c, 0, 0, 0);
}

struct alignas(16) F4 { float a, b, c, d; };
struct alignas(8) U4 { ushort_t a, b, c, d; };

#define QSCALE 0.18033688011112043f /* 0.125 * log2(e): softmax in exp2 domain */

// ---------------- fused prep: x fp32->bf16 + 4x LoRA merge ----------------
__global__ __launch_bounds__(256) void prep_kernel(
    const float* __restrict__ x, ushort_t* __restrict__ xs,
    const float* __restrict__ W0, const float* __restrict__ dW0, const float* __restrict__ dB0,
    const float* __restrict__ W1, const float* __restrict__ dW1, const float* __restrict__ dB1,
    const float* __restrict__ W2, const float* __restrict__ dW2, const float* __restrict__ dB2,
    const float* __restrict__ W3, const float* __restrict__ dW3, const float* __restrict__ dB3,
    ushort_t* __restrict__ Wm) {
  const int bid = blockIdx.x;
  if (bid < 4096) {
    int i = bid * 256 + threadIdx.x;
    F4 v = ((const F4*)x)[i];
    U4 hh = {f2bf(v.a), f2bf(v.b), f2bf(v.c), f2bf(v.d)};
    ((U4*)xs)[i] = hh;
    return;
  }
  const int t = bid - 4096;
  const int layer = t >> 7, sub = t & 127;
  const float* W = (layer == 0) ? W0 : (layer == 1) ? W1 : (layer == 2) ? W2 : W3;
  const float* dW = (layer == 0) ? dW0 : (layer == 1) ? dW1 : (layer == 2) ? dW2 : dW3;
  const float* dB = (layer == 0) ? dB0 : (layer == 1) ? dB1 : (layer == 2) ? dB2 : dB3;
  ushort_t* Wh = Wm + (size_t)layer * 1024 * 1024;
  const int ot = sub * 8;
  const int d0 = threadIdx.x * 4;
  float acc[8][4] = {};
  for (int r = 0; r < 32; ++r) {
    F4 w = *(const F4*)&dW[r * 1024 + d0];
    float wv[4] = {w.a, w.b, w.c, w.d};
#pragma unroll
    for (int o = 0; o < 8; ++o) {
      float s = dB[(ot + o) * 32 + r];
#pragma unroll
      for (int j = 0; j < 4; ++j) acc[o][j] += s * wv[j];
    }
  }
#pragma unroll
  for (int o = 0; o < 8; ++o) {
    F4 w = *(const F4*)&W[(ot + o) * 1024 + d0];
    U4 hh = {f2bf(w.a + acc[o][0]), f2bf(w.b + acc[o][1]),
             f2bf(w.c + acc[o][2]), f2bf(w.d + acc[o][3])};
    *(U4*)&Wh[(ot + o) * 1024 + d0] = hh;
  }
}

// ---------------- bf16 GEMM, double-buffered: C = A @ B^T + bias ----------------
// Tile 128(M) x TN(N).
// MODE 0 (TN=128): QK GEMM. N=2048. Q cols (<1024) scaled by QSCALE; bias b0/b1.
// MODE 2 (TN=128): V^T GEMM per batch z: A=Wv[1024][1024], B=xs_z[2048][1024],
//                  C=vt+z*1024*2048, bias b0[row]. Coalesced 32B-run stores.
// MODE 1 (TN=64):  fp32 out, bias b0[col].
template <int MODE, int TN>
__global__ __launch_bounds__(256) void gemm_bt(
    const ushort_t* __restrict__ A, const ushort_t* __restrict__ B,
    const float* __restrict__ b0, const float* __restrict__ b1,
    ushort_t* __restrict__ C, float* __restrict__ Cf,
    const int M, const int N, const int K) {
  constexpr int NT2 = TN / 32;  // acc col-tiles per wave
  __shared__ __align__(16) ushort_t lA[2][128 * 32], lB[2][TN * 32];
  const int tid = threadIdx.x;
  const int wave = tid >> 6, lane = tid & 63;
  const int lo4 = lane & 15, quad = lane >> 4;
  const int n0 = blockIdx.x * TN, m0 = blockIdx.y * 128;
  const int wm = (wave >> 1) * 64, wn = (wave & 1) * (TN / 2);

  if (MODE == 2) {  // per-batch offsets
    B += (size_t)blockIdx.z * 2048 * 1024;
    C += (size_t)blockIdx.z * 1024 * 2048;
  }

  floatx4 acc[4][NT2];
  const floatx4 zero4 = {0.f, 0.f, 0.f, 0.f};
#pragma unroll
  for (int mt = 0; mt < 4; ++mt)
#pragma unroll
    for (int nt = 0; nt < NT2; ++nt) acc[mt][nt] = zero4;

  const int strow = lane >> 2;       // 0..15
  const int stcol = (lane & 3) * 8;  // 0,8,16,24

  const int NTILES = K >> 5;
  {
#pragma unroll
    for (int i = 0; i < 2; ++i) {
      const int g = wave * 2 + i;
      async_copy16(&lA[0][g * 512], A + (size_t)(m0 + g * 16 + strow) * K + stcol);
    }
#pragma unroll
    for (int i = 0; i < TN / 64; ++i) {
      const int g = wave * (TN / 64) + i;
      async_copy16(&lB[0][g * 512], B + (size_t)(n0 + g * 16 + strow) * K + stcol);
    }
  }
  __syncthreads();

  for (int t = 0; t < NTILES; ++t) {
    const int cur = t & 1;
    if (t + 1 < NTILES) {
      const int kk = (t + 1) << 5;
#pragma unroll
      for (int i = 0; i < 2; ++i) {
        const int g = wave * 2 + i;
        async_copy16(&lA[cur ^ 1][g * 512], A + (size_t)(m0 + g * 16 + strow) * K + kk + stcol);
      }
#pragma unroll
      for (int i = 0; i < TN / 64; ++i) {
        const int g = wave * (TN / 64) + i;
        async_copy16(&lB[cur ^ 1][g * 512], B + (size_t)(n0 + g * 16 + strow) * K + kk + stcol);
      }
    }
    short8 a_[4], b_[NT2];
#pragma unroll
    for (int t2 = 0; t2 < 4; ++t2)
      a_[t2] = *(const short8*)&lA[cur][(wm + t2 * 16 + lo4) * 32 + quad * 8];
#pragma unroll
    for (int t2 = 0; t2 < NT2; ++t2)
      b_[t2] = *(const short8*)&lB[cur][(wn + t2 * 16 + lo4) * 32 + quad * 8];
#pragma unroll
    for (int mt = 0; mt < 4; ++mt)
#pragma unroll
      for (int nt = 0; nt < NT2; ++nt) acc[mt][nt] = mfma16(a_[mt], b_[nt], acc[mt][nt]);
    if (t + 1 < NTILES) __syncthreads();
  }

#pragma unroll
  for (int nt = 0; nt < NT2; ++nt) {
    const int col = n0 + wn + nt * 16 + lo4;
    float cbias = 0.f;
    if (MODE == 0) cbias = (col < 1024) ? b0[col] : b1[col - 1024];
    if (MODE == 1) cbias = b0[col];
#pragma unroll
    for (int mt = 0; mt < 4; ++mt)
#pragma unroll
      for (int r = 0; r < 4; ++r) {
        const int row = m0 + wm + mt * 16 + quad * 4 + r;
        float c = acc[mt][nt][r] + (MODE == 2 ? b0[row] : cbias);
        if (MODE == 0) {
          if (col < 1024) c *= QSCALE;  // pre-scale Q for exp2-domain softmax
          C[(size_t)row * 2048 + col] = f2bf(c);
        } else if (MODE == 2) {
          C[(size_t)row * 2048 + col] = f2bf(c);
        } else {
          Cf[(size_t)row * N + col] = c;
        }
      }
  }
}

// ---------------- flash attention, dbuf K/V, mt=2, max-free exp2 softmax ----------
// grid (qt=16, bh=32) = 512 blocks (2/CU), 256 threads. Wave w owns q-rows
// w*32..+32 (two 16-row m-tiles). All 4 waves share one 64-key K/V tile (dbuf,
// one barrier/iter). K frag read once feeds 2 MFMAs; same for V. XOR-swizzled.
__global__ __launch_bounds__(256) void attn_kernel(
    const ushort_t* __restrict__ qk, const ushort_t* __restrict__ vt,
    ushort_t* __restrict__ at) {
  __shared__ __align__(16) ushort_t Kh[2][64 * 64], Vh[2][64 * 64];  // 16 KB each
  __shared__ __align__(16) ushort_t P[4][32][68];                    // 17 KB
  const int qt = blockIdx.x, bh = blockIdx.y;
  const int b = bh >> 4, h = bh & 15;
  const int tid = threadIdx.x;
  const int wave = tid >> 6, lane = tid & 63;
  const int lo4 = lane & 15, quad = lane >> 4;

  // Q fragments (A-operand layout), pre-scaled by QSCALE; 2 m-tiles
  short8 qh[2][2];
#pragma unroll
  for (int mt = 0; mt < 2; ++mt) {
    const size_t g =
        (size_t)(b * 2048 + qt * 128 + wave * 32 + mt * 16 + lo4) * 2048 + h * 64 + quad * 8;
    qh[mt][0] = *(const short8*)(qk + g);
    qh[mt][1] = *(const short8*)(qk + g + 32);
  }
  float l_acc[2][4] = {};
  const floatx4 zero4 = {0.f, 0.f, 0.f, 0.f};
  floatx4 O[2][4];
#pragma unroll
  for (int mt = 0; mt < 2; ++mt)
#pragma unroll
    for (int nt = 0; nt < 4; ++nt) O[mt][nt] = zero4;

  const int strow = lane >> 3;                 // 0..7
  const int stcol = ((lane & 7) ^ strow) * 8;  // swizzled source chunk

  // prologue: stage tile 0 into buf 0 (each wave stages 16 of the 64 rows)
#pragma unroll
  for (int i = 0; i < 2; ++i) {
    const int row = wave * 16 + i * 8 + strow;  // row & 7 == strow
    const int uoff = (wave * 16 + i * 8) * 64;
    async_copy16(&Kh[0][uoff], qk + (size_t)(b * 2048 + row) * 2048 + 1024 + h * 64 + stcol);
    async_copy16(&Vh[0][uoff], vt + (size_t)(bh * 64 + row) * 2048 + stcol);
  }
  __syncthreads();

  for (int kt = 0; kt < 32; ++kt) {
    const int cur = kt & 1;
    if (kt + 1 < 32) {  // prefetch next K/V tile
      const int kn = (kt + 1) * 64;
#pragma unroll
      for (int i = 0; i < 2; ++i) {
        const int row = wave * 16 + i * 8 + strow;
        const int uoff = (wave * 16 + i * 8) * 64;
        async_copy16(&Kh[cur ^ 1][uoff],
                     qk + (size_t)(b * 2048 + kn + row) * 2048 + 1024 + h * 64 + stcol);
        async_copy16(&Vh[cur ^ 1][uoff], vt + (size_t)(bh * 64 + row) * 2048 + kn + stcol);
      }
    }

    // S = Q @ K^T for both m-tiles; each K frag read once
    floatx4 s[2][4];
#pragma unroll
    for (int mt = 0; mt < 2; ++mt)
#pragma unroll
      for (int nt = 0; nt < 4; ++nt) s[mt][nt] = zero4;
#pragma unroll
    for (int nt = 0; nt < 4; ++nt)
#pragma unroll
      for (int ks = 0; ks < 2; ++ks) {
        const int off = (nt * 16 + lo4) * 64 + (((ks * 4 + quad) ^ (lo4 & 7)) * 8);
        short8 kf = *(const short8*)&Kh[cur][off];
        s[0][nt] = mfma16(qh[0][ks], kf, s[0][nt]);
        s[1][nt] = mfma16(qh[1][ks], kf, s[1][nt]);
      }

    // p = exp2(s); per-lane l; P as truncated bf16
#pragma unroll
    for (int mt = 0; mt < 2; ++mt) {
#pragma unroll
      for (int nt = 0; nt < 4; ++nt)
#pragma unroll
        for (int r = 0; r < 4; ++r) {
          float pv = __builtin_amdgcn_exp2f(s[mt][nt][r]);
          s[mt][nt][r] = pv;
          P[wave][mt * 16 + quad * 4 + r][nt * 16 + lo4] =
              (ushort_t)(__float_as_uint(pv) >> 16);
        }
#pragma unroll
      for (int r = 0; r < 4; ++r)
        l_acc[mt][r] += (s[mt][0][r] + s[mt][1][r]) + (s[mt][2][r] + s[mt][3][r]);
    }

    // O += P @ V ; each V frag read once feeds both m-tiles
#pragma unroll
    for (int ks = 0; ks < 2; ++ks) {
      short8 pf0 = *(const short8*)&P[wave][lo4][ks * 32 + quad * 8];
      short8 pf1 = *(const short8*)&P[wave][16 + lo4][ks * 32 + quad * 8];
#pragma unroll
      for (int nt = 0; nt < 4; ++nt) {
        const int off = (nt * 16 + lo4) * 64 + (((ks * 4 + quad) ^ (lo4 & 7)) * 8);
        short8 vf = *(const short8*)&Vh[cur][off];
        O[0][nt] = mfma16(pf0, vf, O[0][nt]);
        O[1][nt] = mfma16(pf1, vf, O[1][nt]);
      }
    }
    if (kt + 1 < 32) __syncthreads();
  }

#pragma unroll
  for (int mt = 0; mt < 2; ++mt) {
    float linv[4];
#pragma unroll
    for (int r = 0; r < 4; ++r) {
      float s = l_acc[mt][r];
      s += __shfl_xor(s, 1);
      s += __shfl_xor(s, 2);
      s += __shfl_xor(s, 4);
      s += __shfl_xor(s, 8);
      linv[r] = 1.f / s;
    }
#pragma unroll
    for (int nt = 0; nt < 4; ++nt)
#pragma unroll
      for (int r = 0; r < 4; ++r) {
        float o = O[mt][nt][r] * linv[r];
        const size_t row =
            (size_t)(b * 2048 + qt * 128 + wave * 32 + mt * 16 + quad * 4 + r);
        at[row * 1024 + h * 64 + nt * 16 + lo4] = f2bf(o);
      }
  }
}

extern "C" void kernel_launch(void* const* d_in, const int* in_sizes, int n_in,
                              void* d_out, int out_size, void* d_ws, size_t ws_size,
                              hipStream_t stream) {
  const float* x = (const float*)d_in[0];
  const float* qW = (const float*)d_in[1];
  const float* qb = (const float*)d_in[2];
  const float* qdW = (const float*)d_in[3];
  const float* qdB = (const float*)d_in[4];
  const float* kW = (const float*)d_in[5];
  const float* kb = (const float*)d_in[6];
  const float* kdW = (const float*)d_in[7];
  const float* kdB = (const float*)d_in[8];
  const float* vW = (const float*)d_in[9];
  const float* vb = (const float*)d_in[10];
  const float* vdW = (const float*)d_in[11];
  const float* vdB = (const float*)d_in[12];
  const float* oW = (const float*)d_in[13];
  const float* ob = (const float*)d_in[14];
  const float* odW = (const float*)d_in[15];
  const float* odB = (const float*)d_in[16];

  char* ws = (char*)d_ws;
  const size_t MB = 1024u * 1024u;
  const size_t WELEM = 1024u * 1024u;
  ushort_t* xs = (ushort_t*)(ws + 0 * MB);   // 8MB  (4096x1024)
  ushort_t* Wm = (ushort_t*)(ws + 8 * MB);   // 8MB  (4x1024x1024)
  ushort_t* qk = (ushort_t*)(ws + 16 * MB);  // 16MB (4096x2048: Q|K, Q pre-scaled)
  ushort_t* vt = (ushort_t*)(ws + 32 * MB);  // 8MB  ([b*1024 + d][token] V^T)
  ushort_t* at = xs;                         // reuse dead x for attention out

  prep_kernel<<<4608, 256, 0, stream>>>(x, xs, qW, qdW, qdB, kW, kdW, kdB,
                                        vW, vdW, vdB, oW, odW, odB, Wm);
  // QK projections: [4096 tok] x [2048 qk-dims]
  gemm_bt<0, 128><<<dim3(16, 32), 256, 0, stream>>>(xs, Wm, qb, kb, qk, nullptr,
                                                    4096, 2048, 1024);
  // V^T: per batch, [1024 d] x [2048 tok]
  gemm_bt<2, 128><<<dim3(16, 8, 2), 256, 0, stream>>>(Wm + 2 * WELEM, xs, vb, nullptr,
                                                      vt, nullptr, 1024, 2048, 1024);
  attn_kernel<<<dim3(16, 32), 256, 0, stream>>>(qk, vt, at);
  gemm_bt<1, 64><<<dim3(16, 32), 256, 0, stream>>>(at, Wm + 3 * WELEM, ob, nullptr,
                                                   nullptr, (float*)d_out,
                                                   4096, 1024, 1024);
}

// Round 7
// 236.097 us; speedup vs baseline: 1.0604x; 1.0604x over previous
//
#include <hip/hip_runtime.h>

typedef unsigned short ushort_t;
typedef unsigned int u32;
typedef __attribute__((ext_vector_type(8))) short short8;
typedef __attribute__((ext_vector_type(4))) float floatx4;

typedef const __attribute__((address_space(1))) u32* gptr_t;
typedef __attribute__((address_space(3))) u32* lptr_t;

__device__ __forceinline__ void async_copy16(void* lds, const void* g) {
  __builtin_amdgcn_global_load_lds((gptr_t)g, (lptr_t)lds, 16, 0, 0);
}

__device__ __forceinline__ ushort_t f2bf(float f) {  // RNE
  u32 u = __float_as_uint(f);
  u += 0x7fffu + ((u >> 16) & 1u);
  return (ushort_t)(u >> 16);
}

__device__ __forceinline__ floatx4 mfma16(short8 a, short8 b, floatx4 c) {
  return __builtin_amdgcn_mfma_f32_16x16x32_bf16(a, b, c, 0, 0, 0);
}

struct alignas(16) F4 { float a, b, c, d; };
struct alignas(8) U4 { ushort_t a, b, c, d; };

#define QSCALE 0.18033688011112043f /* 0.125 * log2(e): softmax in exp2 domain */

// ---------------- fused prep: x fp32->bf16 + 4x LoRA merge ----------------
__global__ __launch_bounds__(256) void prep_kernel(
    const float* __restrict__ x, ushort_t* __restrict__ xs,
    const float* __restrict__ W0, const float* __restrict__ dW0, const float* __restrict__ dB0,
    const float* __restrict__ W1, const float* __restrict__ dW1, const float* __restrict__ dB1,
    const float* __restrict__ W2, const float* __restrict__ dW2, const float* __restrict__ dB2,
    const float* __restrict__ W3, const float* __restrict__ dW3, const float* __restrict__ dB3,
    ushort_t* __restrict__ Wm) {
  const int bid = blockIdx.x;
  if (bid < 4096) {
    int i = bid * 256 + threadIdx.x;
    F4 v = ((const F4*)x)[i];
    U4 hh = {f2bf(v.a), f2bf(v.b), f2bf(v.c), f2bf(v.d)};
    ((U4*)xs)[i] = hh;
    return;
  }
  const int t = bid - 4096;
  const int layer = t >> 7, sub = t & 127;
  const float* W = (layer == 0) ? W0 : (layer == 1) ? W1 : (layer == 2) ? W2 : W3;
  const float* dW = (layer == 0) ? dW0 : (layer == 1) ? dW1 : (layer == 2) ? dW2 : dW3;
  const float* dB = (layer == 0) ? dB0 : (layer == 1) ? dB1 : (layer == 2) ? dB2 : dB3;
  ushort_t* Wh = Wm + (size_t)layer * 1024 * 1024;
  const int ot = sub * 8;
  const int d0 = threadIdx.x * 4;
  float acc[8][4] = {};
  for (int r = 0; r < 32; ++r) {
    F4 w = *(const F4*)&dW[r * 1024 + d0];
    float wv[4] = {w.a, w.b, w.c, w.d};
#pragma unroll
    for (int o = 0; o < 8; ++o) {
      float s = dB[(ot + o) * 32 + r];
#pragma unroll
      for (int j = 0; j < 4; ++j) acc[o][j] += s * wv[j];
    }
  }
#pragma unroll
  for (int o = 0; o < 8; ++o) {
    F4 w = *(const F4*)&W[(ot + o) * 1024 + d0];
    U4 hh = {f2bf(w.a + acc[o][0]), f2bf(w.b + acc[o][1]),
             f2bf(w.c + acc[o][2]), f2bf(w.d + acc[o][3])};
    *(U4*)&Wh[(ot + o) * 1024 + d0] = hh;
  }
}

// ------------- merged QK + V^T GEMM (dbuf, 128x128 tile, K=1024) -------------
// grid (16, 48): y<32 -> QK: C[4096 tok][2048 qk-dims], Q cols scaled, Q->qx
// row-major, K cols -> kx[bh][tok][64] contiguous; y>=32 -> V^T per batch z:
// A=Wv, B=xs_z, out -> vt tiled [bh][tile32][64d][64tok] (8 KB contiguous tiles).
__global__ __launch_bounds__(256) void gemm_qkvt(
    const ushort_t* __restrict__ xs, const ushort_t* __restrict__ Wm,
    const float* __restrict__ qb, const float* __restrict__ kb,
    const float* __restrict__ vb,
    ushort_t* __restrict__ qx, ushort_t* __restrict__ kx,
    ushort_t* __restrict__ vt) {
  __shared__ __align__(16) ushort_t lA[2][128 * 32], lB[2][128 * 32];
  const int tid = threadIdx.x;
  const int wave = tid >> 6, lane = tid & 63;
  const int lo4 = lane & 15, quad = lane >> 4;
  const int n0 = blockIdx.x * 128;
  const int wm = (wave >> 1) * 64, wn = (wave & 1) * 64;

  const bool isVT = blockIdx.y >= 32;
  const ushort_t* A;
  const ushort_t* B;
  int m0, z = 0;
  if (!isVT) {
    A = xs;            // [4096][1024]
    B = Wm;            // rows 0..2047 = Wq|Wk
    m0 = blockIdx.y * 128;
  } else {
    const int t = blockIdx.y - 32;
    z = t >> 3;
    A = Wm + 2u * 1024 * 1024;            // Wv [1024][1024]
    B = xs + (size_t)z * 2048 * 1024;     // tokens of batch z
    m0 = (t & 7) * 128;
  }

  floatx4 acc[4][4];
  const floatx4 zero4 = {0.f, 0.f, 0.f, 0.f};
#pragma unroll
  for (int mt = 0; mt < 4; ++mt)
#pragma unroll
    for (int nt = 0; nt < 4; ++nt) acc[mt][nt] = zero4;

  const int strow = lane >> 2;       // 0..15
  const int stcol = (lane & 3) * 8;  // 0,8,16,24

  {
#pragma unroll
    for (int i = 0; i < 2; ++i) {
      const int g = wave * 2 + i;
      async_copy16(&lA[0][g * 512], A + (size_t)(m0 + g * 16 + strow) * 1024 + stcol);
      async_copy16(&lB[0][g * 512], B + (size_t)(n0 + g * 16 + strow) * 1024 + stcol);
    }
  }
  __syncthreads();

  for (int t = 0; t < 32; ++t) {
    const int cur = t & 1;
    if (t + 1 < 32) {
      const int kk = (t + 1) << 5;
#pragma unroll
      for (int i = 0; i < 2; ++i) {
        const int g = wave * 2 + i;
        async_copy16(&lA[cur ^ 1][g * 512], A + (size_t)(m0 + g * 16 + strow) * 1024 + kk + stcol);
        async_copy16(&lB[cur ^ 1][g * 512], B + (size_t)(n0 + g * 16 + strow) * 1024 + kk + stcol);
      }
    }
    short8 a_[4], b_[4];
#pragma unroll
    for (int t2 = 0; t2 < 4; ++t2) {
      a_[t2] = *(const short8*)&lA[cur][(wm + t2 * 16 + lo4) * 32 + quad * 8];
      b_[t2] = *(const short8*)&lB[cur][(wn + t2 * 16 + lo4) * 32 + quad * 8];
    }
#pragma unroll
    for (int mt = 0; mt < 4; ++mt)
#pragma unroll
      for (int nt = 0; nt < 4; ++nt) acc[mt][nt] = mfma16(a_[mt], b_[nt], acc[mt][nt]);
    if (t + 1 < 32) __syncthreads();
  }

#pragma unroll
  for (int nt = 0; nt < 4; ++nt) {
    const int col = n0 + wn + nt * 16 + lo4;
#pragma unroll
    for (int mt = 0; mt < 4; ++mt)
#pragma unroll
      for (int r = 0; r < 4; ++r) {
        const int row = m0 + wm + mt * 16 + quad * 4 + r;
        if (!isVT) {
          float c = acc[mt][nt][r] + ((col < 1024) ? qb[col] : kb[col - 1024]);
          if (col < 1024) {
            c *= QSCALE;  // pre-scale Q for exp2-domain softmax
            qx[(size_t)row * 1024 + col] = f2bf(c);
          } else {
            const int d = col - 1024;
            // kx[bh][tok][64]: bh = b*16 + head
            kx[(size_t)((row >> 11) * 16 + (d >> 6)) * 131072 + (size_t)(row & 2047) * 64 +
               (d & 63)] = f2bf(c);
          }
        } else {
          float c = acc[mt][nt][r] + vb[row];  // row = d-dim
          // vt[bh][tile][64d][64tok]
          vt[(size_t)(((z * 16 + (row >> 6)) * 32 + (col >> 6)) * 4096) +
             (size_t)(row & 63) * 64 + (col & 63)] = f2bf(c);
        }
      }
  }
}

// ---------------- output GEMM: fp32 C = A @ B^T + bias, 128x64 tile -----------
__global__ __launch_bounds__(256) void gemm_out(
    const ushort_t* __restrict__ A, const ushort_t* __restrict__ B,
    const float* __restrict__ bias, float* __restrict__ Cf) {
  __shared__ __align__(16) ushort_t lA[2][128 * 32], lB[2][64 * 32];
  const int tid = threadIdx.x;
  const int wave = tid >> 6, lane = tid & 63;
  const int lo4 = lane & 15, quad = lane >> 4;
  const int n0 = blockIdx.x * 64, m0 = blockIdx.y * 128;
  const int wm = (wave >> 1) * 64, wn = (wave & 1) * 32;

  floatx4 acc[4][2];
  const floatx4 zero4 = {0.f, 0.f, 0.f, 0.f};
#pragma unroll
  for (int mt = 0; mt < 4; ++mt)
#pragma unroll
    for (int nt = 0; nt < 2; ++nt) acc[mt][nt] = zero4;

  const int strow = lane >> 2;
  const int stcol = (lane & 3) * 8;

  {
#pragma unroll
    for (int i = 0; i < 2; ++i) {
      const int g = wave * 2 + i;
      async_copy16(&lA[0][g * 512], A + (size_t)(m0 + g * 16 + strow) * 1024 + stcol);
    }
    async_copy16(&lB[0][wave * 512], B + (size_t)(n0 + wave * 16 + strow) * 1024 + stcol);
  }
  __syncthreads();

  for (int t = 0; t < 32; ++t) {
    const int cur = t & 1;
    if (t + 1 < 32) {
      const int kk = (t + 1) << 5;
#pragma unroll
      for (int i = 0; i < 2; ++i) {
        const int g = wave * 2 + i;
        async_copy16(&lA[cur ^ 1][g * 512], A + (size_t)(m0 + g * 16 + strow) * 1024 + kk + stcol);
      }
      async_copy16(&lB[cur ^ 1][wave * 512],
                   B + (size_t)(n0 + wave * 16 + strow) * 1024 + kk + stcol);
    }
    short8 a_[4], b_[2];
#pragma unroll
    for (int t2 = 0; t2 < 4; ++t2)
      a_[t2] = *(const short8*)&lA[cur][(wm + t2 * 16 + lo4) * 32 + quad * 8];
#pragma unroll
    for (int t2 = 0; t2 < 2; ++t2)
      b_[t2] = *(const short8*)&lB[cur][(wn + t2 * 16 + lo4) * 32 + quad * 8];
#pragma unroll
    for (int mt = 0; mt < 4; ++mt)
#pragma unroll
      for (int nt = 0; nt < 2; ++nt) acc[mt][nt] = mfma16(a_[mt], b_[nt], acc[mt][nt]);
    if (t + 1 < 32) __syncthreads();
  }

#pragma unroll
  for (int nt = 0; nt < 2; ++nt) {
    const int col = n0 + wn + nt * 16 + lo4;
    const float cb = bias[col];
#pragma unroll
    for (int mt = 0; mt < 4; ++mt)
#pragma unroll
      for (int r = 0; r < 4; ++r) {
        const int row = m0 + wm + mt * 16 + quad * 4 + r;
        Cf[(size_t)row * 1024 + col] = acc[mt][nt][r] + cb;
      }
  }
}

// ---------------- flash attention, contiguous tiles, dbuf, exp2 softmax ----------
// grid (bh=32, qt=16): linear id % 8 == bh % 8 -> all q-blocks of one head on one
// XCD (K/V served from its L2). 512 threads; wave w owns q-rows w*16..+16; 8 waves
// share one 64-key K/V tile (each 8 KB CONTIGUOUS in global), double-buffered.
__global__ __launch_bounds__(512) void attn_kernel(
    const ushort_t* __restrict__ qx, const ushort_t* __restrict__ kx,
    const ushort_t* __restrict__ vt, ushort_t* __restrict__ at) {
  __shared__ __align__(16) ushort_t Kh[2][64 * 64], Vh[2][64 * 64];  // 16 KB each
  __shared__ __align__(16) ushort_t P[8][16][72];                    // 18 KB
  const int bh = blockIdx.x, qt = blockIdx.y;
  const int b = bh >> 4, h = bh & 15;
  const int tid = threadIdx.x;
  const int wave = tid >> 6, lane = tid & 63;
  const int lo4 = lane & 15, quad = lane >> 4;

  // Q fragments (A-operand layout), pre-scaled by QSCALE
  short8 qh[2];
  {
    const size_t g = (size_t)(b * 2048 + qt * 128 + wave * 16 + lo4) * 1024 + h * 64 + quad * 8;
    qh[0] = *(const short8*)(qx + g);
    qh[1] = *(const short8*)(qx + g + 32);
  }
  float l_acc[4] = {0.f, 0.f, 0.f, 0.f};
  const floatx4 zero4 = {0.f, 0.f, 0.f, 0.f};
  floatx4 O[4];
#pragma unroll
  for (int nt = 0; nt < 4; ++nt) O[nt] = zero4;

  const int strow = lane >> 3;                 // 0..7
  const int csw = ((lane & 7) ^ strow) * 8;    // swizzled chunk within 128B row
  const size_t kbase = (size_t)bh * 131072;    // kx[bh][2048][64]
  const size_t vbase = (size_t)bh * 32 * 4096; // vt[bh][32][64][64]
  const int srow = wave * 8 + strow;           // wave stages rows wave*8..+8
  const int uoff = wave * 512;

  // prologue: tile 0 -> buf 0 (fully coalesced: each wave reads 1 KB contiguous)
  async_copy16(&Kh[0][uoff], kx + kbase + (size_t)srow * 64 + csw);
  async_copy16(&Vh[0][uoff], vt + vbase + (size_t)srow * 64 + csw);
  __syncthreads();

  for (int kt = 0; kt < 32; ++kt) {
    const int cur = kt & 1;
    if (kt + 1 < 32) {  // prefetch next contiguous 8 KB K/V tiles
      async_copy16(&Kh[cur ^ 1][uoff],
                   kx + kbase + (size_t)((kt + 1) * 64 + srow) * 64 + csw);
      async_copy16(&Vh[cur ^ 1][uoff],
                   vt + vbase + (size_t)(kt + 1) * 4096 + (size_t)srow * 64 + csw);
    }

    // S = Q @ K^T (exp2 domain)
    floatx4 s[4];
#pragma unroll
    for (int nt = 0; nt < 4; ++nt) s[nt] = zero4;
#pragma unroll
    for (int nt = 0; nt < 4; ++nt)
#pragma unroll
      for (int ks = 0; ks < 2; ++ks) {
        const int off = (nt * 16 + lo4) * 64 + (((ks * 4 + quad) ^ (lo4 & 7)) * 8);
        s[nt] = mfma16(qh[ks], *(const short8*)&Kh[cur][off], s[nt]);
      }

    // p = exp2(s); per-lane l; P as truncated bf16
#pragma unroll
    for (int nt = 0; nt < 4; ++nt)
#pragma unroll
      for (int r = 0; r < 4; ++r) {
        float pv = __builtin_amdgcn_exp2f(s[nt][r]);
        s[nt][r] = pv;
        P[wave][quad * 4 + r][nt * 16 + lo4] = (ushort_t)(__float_as_uint(pv) >> 16);
      }
#pragma unroll
    for (int r = 0; r < 4; ++r)
      l_acc[r] += (s[0][r] + s[1][r]) + (s[2][r] + s[3][r]);

    // O += P @ V  (P round-trip in per-wave LDS region: no barrier)
#pragma unroll
    for (int ks = 0; ks < 2; ++ks) {
      short8 pf = *(const short8*)&P[wave][lo4][ks * 32 + quad * 8];
#pragma unroll
      for (int nt = 0; nt < 4; ++nt) {
        const int off = (nt * 16 + lo4) * 64 + (((ks * 4 + quad) ^ (lo4 & 7)) * 8);
        O[nt] = mfma16(pf, *(const short8*)&Vh[cur][off], O[nt]);
      }
    }
    if (kt + 1 < 32) __syncthreads();
  }

  float linv[4];
#pragma unroll
  for (int r = 0; r < 4; ++r) {
    float s = l_acc[r];
    s += __shfl_xor(s, 1);
    s += __shfl_xor(s, 2);
    s += __shfl_xor(s, 4);
    s += __shfl_xor(s, 8);
    linv[r] = 1.f / s;
  }
#pragma unroll
  for (int nt = 0; nt < 4; ++nt)
#pragma unroll
    for (int r = 0; r < 4; ++r) {
      float o = O[nt][r] * linv[r];
      const size_t row = (size_t)(b * 2048 + qt * 128 + wave * 16 + quad * 4 + r);
      at[row * 1024 + h * 64 + nt * 16 + lo4] = f2bf(o);
    }
}

extern "C" void kernel_launch(void* const* d_in, const int* in_sizes, int n_in,
                              void* d_out, int out_size, void* d_ws, size_t ws_size,
                              hipStream_t stream) {
  const float* x = (const float*)d_in[0];
  const float* qW = (const float*)d_in[1];
  const float* qb = (const float*)d_in[2];
  const float* qdW = (const float*)d_in[3];
  const float* qdB = (const float*)d_in[4];
  const float* kW = (const float*)d_in[5];
  const float* kb = (const float*)d_in[6];
  const float* kdW = (const float*)d_in[7];
  const float* kdB = (const float*)d_in[8];
  const float* vW = (const float*)d_in[9];
  const float* vb = (const float*)d_in[10];
  const float* vdW = (const float*)d_in[11];
  const float* vdB = (const float*)d_in[12];
  const float* oW = (const float*)d_in[13];
  const float* ob = (const float*)d_in[14];
  const float* odW = (const float*)d_in[15];
  const float* odB = (const float*)d_in[16];

  char* ws = (char*)d_ws;
  const size_t MB = 1024u * 1024u;
  const size_t WELEM = 1024u * 1024u;
  ushort_t* xs = (ushort_t*)(ws + 0 * MB);   // 8MB  (4096x1024)
  ushort_t* Wm = (ushort_t*)(ws + 8 * MB);   // 8MB  (4x1024x1024)
  ushort_t* qx = (ushort_t*)(ws + 16 * MB);  // 8MB  (4096x1024, pre-scaled Q)
  ushort_t* kx = (ushort_t*)(ws + 24 * MB);  // 8MB  ([bh][2048][64] contiguous)
  ushort_t* vt = (ushort_t*)(ws + 32 * MB);  // 8MB  ([bh][32][64][64] tiled V^T)
  ushort_t* at = xs;                         // reuse dead x for attention out

  prep_kernel<<<4608, 256, 0, stream>>>(x, xs, qW, qdW, qdB, kW, kdW, kdB,
                                        vW, vdW, vdB, oW, odW, odB, Wm);
  gemm_qkvt<<<dim3(16, 48), 256, 0, stream>>>(xs, Wm, qb, kb, vb, qx, kx, vt);
  attn_kernel<<<dim3(32, 16), 512, 0, stream>>>(qx, kx, vt, at);
  gemm_out<<<dim3(16, 32), 256, 0, stream>>>(at, Wm + 3 * WELEM, ob, (float*)d_out);
}